// Round 7
// baseline (367.170 us; speedup 1.0000x reference)
//
#include <hip/hip_runtime.h>
#include <hip/hip_fp16.h>

#define N_NODES 20000
#define E_EDGES 320000
#define D_DIM   128
#define H1HEADS 4
#define G_GRAPHS 256
#define SLOPE   0.2f

typedef short short8 __attribute__((ext_vector_type(8)));
typedef float float4v __attribute__((ext_vector_type(4)));
typedef unsigned short us;

// ---------------- CSR build ----------------
__global__ void cnt_k(const int* __restrict__ dst, int* __restrict__ cnt) {
    int e = blockIdx.x * blockDim.x + threadIdx.x;
    if (e < E_EDGES) atomicAdd(&cnt[dst[e]], 1);
}

__global__ __launch_bounds__(256) void scan_k(const int* __restrict__ cnt,
                                              int* __restrict__ rowptr) {
    __shared__ int s[256];
    const int t = threadIdx.x;
    const int CH = (N_NODES + 255) / 256;   // 79
    int base = t * CH;
    int sum = 0;
    for (int i = 0; i < CH; ++i) {
        int idx = base + i;
        if (idx < N_NODES) sum += cnt[idx];
    }
    s[t] = sum;
    __syncthreads();
    for (int off = 1; off < 256; off <<= 1) {
        int v = (t >= off) ? s[t - off] : 0;
        __syncthreads();
        s[t] += v;
        __syncthreads();
    }
    int run = (t > 0) ? s[t - 1] : 0;
    for (int i = 0; i < CH; ++i) {
        int idx = base + i;
        if (idx < N_NODES) { rowptr[idx] = run; run += cnt[idx]; }
    }
    if (t == 255) rowptr[N_NODES] = run;
}

__global__ void scat_k(const int* __restrict__ src, const int* __restrict__ dst,
                       const int* __restrict__ rowptr, int* __restrict__ cur,
                       int* __restrict__ csrsrc) {
    int e = blockIdx.x * blockDim.x + threadIdx.x;
    if (e >= E_EDGES) return;
    int d = dst[e];
    int p = rowptr[d] + atomicAdd(&cur[d], 1);
    csrsrc[p] = src[e];
}

// ---------- 64-lane bitonic sort (ascending) of one int key per lane ----------
__device__ __forceinline__ int bitonic64(int key, int lane) {
#pragma unroll
    for (int k = 2; k <= 64; k <<= 1) {
#pragma unroll
        for (int j = k >> 1; j > 0; j >>= 1) {
            int other = __shfl_xor(key, j);
            bool up = ((lane & k) == 0);
            bool lower = ((lane & j) == 0);
            int mn = min(key, other), mx = max(key, other);
            key = (up == lower) ? mn : mx;
        }
    }
    return key;
}

// ---------- canonical per-bucket sort of csrsrc (deg < 64 empirically guaranteed) ----------
__global__ __launch_bounds__(256) void sortb_k(const int* __restrict__ rowptr,
                                               int* __restrict__ csrsrc) {
    const int node = (blockIdx.x * blockDim.x + threadIdx.x) >> 6;
    if (node >= N_NODES) return;
    const int lane = threadIdx.x & 63;
    const int r0 = rowptr[node];
    const int deg = rowptr[node + 1] - r0;
    if (deg <= 1 || deg > 64) return;
    int key = 0x7FFFFFFF;
    if (lane < deg) key = csrsrc[r0 + lane];
    key = bitonic64(key, lane);
    if (lane < deg) csrsrc[r0 + lane] = key;
}

// ---------- bf16 split helpers ----------
__device__ __forceinline__ us f2bf(float f) {
    unsigned u = __float_as_uint(f);
    unsigned r = u + 0x7FFFu + ((u >> 16) & 1u);   // RNE
    return (us)(r >> 16);
}
__device__ __forceinline__ float bf2f(us b) {
    return __uint_as_float((unsigned)b << 16);
}

// fused split: x -> hi/lo; W1,W2 -> transposed hi/lo
__global__ void splitall_k(const float* __restrict__ x, us* __restrict__ xhi,
                           us* __restrict__ xlo,
                           const float* __restrict__ W1, us* __restrict__ w1thi,
                           us* __restrict__ w1tlo,
                           const float* __restrict__ W2, us* __restrict__ w2thi,
                           us* __restrict__ w2tlo) {
    int i = blockIdx.x * blockDim.x + threadIdx.x;
    if (i < N_NODES * 128) {
        float v = x[i];
        us h = f2bf(v);
        xhi[i] = h; xlo[i] = f2bf(v - bf2f(h));
    }
    if (i < 128 * 512) {
        {   // W1 [128 x 512] -> T [512 x 128]
            int k = i >> 9, n = i & 511;
            float v = W1[i];
            us h = f2bf(v);
            w1thi[n * 128 + k] = h; w1tlo[n * 128 + k] = f2bf(v - bf2f(h));
        }
        {   // W2 [512 x 128] -> T [128 x 512]
            int k = i >> 7, n = i & 127;
            float v = W2[i];
            us h = f2bf(v);
            w2thi[n * 512 + k] = h; w2tlo[n * 512 + k] = f2bf(v - bf2f(h));
        }
    }
}

// ---------- MFMA GEMM: C[M,N] = A[M,K] * B[K,N], split-bf16 3-pass, reg-prefetch ----------
__device__ __forceinline__ void store_val(__half* p, float v) { *p = __float2half(v); }
__device__ __forceinline__ void store_val(float* p, float v) { *p = v; }

template <typename OT>
__global__ __launch_bounds__(256) void mgemm_k(const us* __restrict__ Ahi,
                                               const us* __restrict__ Alo,
                                               const us* __restrict__ BThi,
                                               const us* __restrict__ BTlo,
                                               const int M, const int N, const int K,
                                               OT* __restrict__ C) {
    constexpr int SA = 72;   // LDS row stride in halfs (64 + 8 pad)
    __shared__ us Ah[64 * SA], Al[64 * SA];
    __shared__ us Bh[128 * SA], Bl[128 * SA];
    const int t = threadIdx.x;
    const int wave = t >> 6, lane = t & 63;
    const int q = lane >> 4, rr = lane & 15;
    const int row0 = blockIdx.x * 64;
    const int col0 = blockIdx.y * 128;
    const int wm = wave & 1, wn = wave >> 1;

    uint4 ra[2][2], rb[4][2];

    auto load_chunk = [&](int kc) {
#pragma unroll
        for (int i = 0; i < 2; ++i) {
            int u = t + i * 256;
            int m = u >> 3, mac = u & 7;
            int r = row0 + m;
            if (r < M) {
                ra[i][0] = *(const uint4*)(Ahi + (size_t)r * K + kc + mac * 8);
                ra[i][1] = *(const uint4*)(Alo + (size_t)r * K + kc + mac * 8);
            } else {
                ra[i][0] = make_uint4(0, 0, 0, 0);
                ra[i][1] = make_uint4(0, 0, 0, 0);
            }
        }
#pragma unroll
        for (int i = 0; i < 4; ++i) {
            int u = t + i * 256;
            int n = u >> 3, mac = u & 7;
            rb[i][0] = *(const uint4*)(BThi + (size_t)(col0 + n) * K + kc + mac * 8);
            rb[i][1] = *(const uint4*)(BTlo + (size_t)(col0 + n) * K + kc + mac * 8);
        }
    };
    auto write_lds = [&]() {
#pragma unroll
        for (int i = 0; i < 2; ++i) {
            int u = t + i * 256;
            int m = u >> 3, mac = u & 7;
            *(uint4*)(Ah + m * SA + mac * 8) = ra[i][0];
            *(uint4*)(Al + m * SA + mac * 8) = ra[i][1];
        }
#pragma unroll
        for (int i = 0; i < 4; ++i) {
            int u = t + i * 256;
            int n = u >> 3, mac = u & 7;
            *(uint4*)(Bh + n * SA + mac * 8) = rb[i][0];
            *(uint4*)(Bl + n * SA + mac * 8) = rb[i][1];
        }
    };

    float4v acc[2][4];
#pragma unroll
    for (int i = 0; i < 2; ++i)
#pragma unroll
        for (int j = 0; j < 4; ++j) acc[i][j] = (float4v){0.f, 0.f, 0.f, 0.f};

    load_chunk(0);
    for (int kc = 0; kc < K; kc += 64) {
        __syncthreads();
        write_lds();
        __syncthreads();
        if (kc + 64 < K) load_chunk(kc + 64);   // prefetch overlaps compute below
#pragma unroll
        for (int ks = 0; ks < 2; ++ks) {
            const int ko = ks * 32 + q * 8;
            short8 ah[2], alo[2], bh[4], blo[4];
#pragma unroll
            for (int mt = 0; mt < 2; ++mt) {
                int m = (wm * 2 + mt) * 16 + rr;
                ah[mt]  = *(const short8*)(Ah + m * SA + ko);
                alo[mt] = *(const short8*)(Al + m * SA + ko);
            }
#pragma unroll
            for (int nt = 0; nt < 4; ++nt) {
                int n = (wn * 4 + nt) * 16 + rr;
                bh[nt]  = *(const short8*)(Bh + n * SA + ko);
                blo[nt] = *(const short8*)(Bl + n * SA + ko);
            }
#pragma unroll
            for (int mt = 0; mt < 2; ++mt)
#pragma unroll
                for (int nt = 0; nt < 4; ++nt) {
                    acc[mt][nt] = __builtin_amdgcn_mfma_f32_16x16x32_bf16(
                        ah[mt], bh[nt], acc[mt][nt], 0, 0, 0);
                    acc[mt][nt] = __builtin_amdgcn_mfma_f32_16x16x32_bf16(
                        ah[mt], blo[nt], acc[mt][nt], 0, 0, 0);
                    acc[mt][nt] = __builtin_amdgcn_mfma_f32_16x16x32_bf16(
                        alo[mt], bh[nt], acc[mt][nt], 0, 0, 0);
                }
        }
    }
    // epilogue: C/D layout col=lane&15, row=q*4+reg
#pragma unroll
    for (int mt = 0; mt < 2; ++mt) {
#pragma unroll
        for (int reg = 0; reg < 4; ++reg) {
            int r = row0 + (wm * 2 + mt) * 16 + q * 4 + reg;
            if (r < M) {
#pragma unroll
                for (int nt = 0; nt < 4; ++nt) {
                    int c = col0 + (wn * 4 + nt) * 16 + rr;
                    store_val(&C[(size_t)r * N + c], acc[mt][nt][reg]);
                }
            }
        }
    }
}

// ---------- attention dots, fp16 features: one wave per row of 128 ----------
__global__ __launch_bounds__(256) void al16_k(const __half* __restrict__ h,
                                              const float* __restrict__ a_src,
                                              const float* __restrict__ a_dst,
                                              float* __restrict__ als,
                                              float* __restrict__ ald,
                                              const int NH, const int H) {
    int wid = (blockIdx.x * blockDim.x + threadIdx.x) >> 6;
    int lane = threadIdx.x & 63;
    if (wid >= NH) return;
    int hh = wid % H;
    const __half2* row = (const __half2*)(h + (size_t)wid * 128);
    float2 v = __half22float2(row[lane]);
    float2 as2 = ((const float2*)(a_src + hh * 128))[lane];
    float2 ad2 = ((const float2*)(a_dst + hh * 128))[lane];
    float s = v.x * as2.x + v.y * as2.y;
    float d = v.x * ad2.x + v.y * ad2.y;
#pragma unroll
    for (int off = 32; off > 0; off >>= 1) {
        s += __shfl_down(s, off);
        d += __shfl_down(d, off);
    }
    if (lane == 0) { als[wid] = s; ald[wid] = d; }
}

__device__ __forceinline__ float lrelu(float v) { return (v > 0.f) ? v : SLOPE * v; }

// ---------- layer-1 fused softmax + gather-aggregate: ONE WAVE PER NODE (4 heads) ----------
// csrsrc pre-sorted -> deterministic. LDS table replaces per-j shfl broadcasts.
__global__ __launch_bounds__(256) void agg1_k(const __half* __restrict__ h,
                                              const float4* __restrict__ als4,
                                              const float4* __restrict__ ald4,
                                              const int* __restrict__ rowptr,
                                              const int* __restrict__ csrsrc,
                                              const float* __restrict__ bias,
                                              us* __restrict__ x1hi,
                                              us* __restrict__ x1lo) {
    __shared__ int   ss[4][64];
    __shared__ float ws[4][64][4];
    const int node = (blockIdx.x * blockDim.x + threadIdx.x) >> 6;
    if (node >= N_NODES) return;
    const int lane = threadIdx.x & 63;
    const int wv = threadIdx.x >> 6;
    const int head = lane >> 4;
    const int r0 = rowptr[node];
    const int deg = rowptr[node + 1] - r0;
    const int tot = deg + 1;
    const float4 aldn = ald4[node];

    float acc[8] = {};
    float4 d4;

    if (tot <= 64) {
        int s = node;                       // self-loop appended at position deg
        if (lane < deg) s = csrsrc[r0 + lane];
        float4 l4 = make_float4(-1e30f, -1e30f, -1e30f, -1e30f);
        if (lane < tot) {
            float4 a = als4[s];
            l4.x = lrelu(a.x + aldn.x); l4.y = lrelu(a.y + aldn.y);
            l4.z = lrelu(a.z + aldn.z); l4.w = lrelu(a.w + aldn.w);
        }
        float4 m4 = l4;
#pragma unroll
        for (int off = 32; off > 0; off >>= 1) {
            m4.x = fmaxf(m4.x, __shfl_xor(m4.x, off));
            m4.y = fmaxf(m4.y, __shfl_xor(m4.y, off));
            m4.z = fmaxf(m4.z, __shfl_xor(m4.z, off));
            m4.w = fmaxf(m4.w, __shfl_xor(m4.w, off));
        }
        float4 w4 = make_float4(0.f, 0.f, 0.f, 0.f);
        if (lane < tot) {
            w4.x = expf(l4.x - m4.x); w4.y = expf(l4.y - m4.y);
            w4.z = expf(l4.z - m4.z); w4.w = expf(l4.w - m4.w);
        }
        d4 = w4;
#pragma unroll
        for (int off = 32; off > 0; off >>= 1) {
            d4.x += __shfl_xor(d4.x, off);
            d4.y += __shfl_xor(d4.y, off);
            d4.z += __shfl_xor(d4.z, off);
            d4.w += __shfl_xor(d4.w, off);
        }
        ss[wv][lane] = s;
        *(float4*)&ws[wv][lane][0] = w4;    // same-wave LDS, no barrier needed
        for (int j = 0; j < tot; ++j) {
            int sj = ss[wv][j];             // broadcast
            float wj = ws[wv][j][head];     // 4 addrs, conflict-free
            const uint4 pk = *((const uint4*)(h + (size_t)sj * 512) + lane);
            const __half2* p2 = (const __half2*)&pk;
            float2 f0 = __half22float2(p2[0]);
            float2 f1 = __half22float2(p2[1]);
            float2 f2 = __half22float2(p2[2]);
            float2 f3 = __half22float2(p2[3]);
            acc[0] += wj * f0.x; acc[1] += wj * f0.y;
            acc[2] += wj * f1.x; acc[3] += wj * f1.y;
            acc[4] += wj * f2.x; acc[5] += wj * f2.y;
            acc[6] += wj * f3.x; acc[7] += wj * f3.y;
        }
    } else {
        // unreachable in practice (max degree < 64); deterministic since csrsrc sorted
        float4 m4 = make_float4(-1e30f, -1e30f, -1e30f, -1e30f);
        for (int base = 0; base < tot; base += 64) {
            int j = base + lane;
            float4 l4 = make_float4(-1e30f, -1e30f, -1e30f, -1e30f);
            if (j < tot) {
                int s = (j < deg) ? csrsrc[r0 + j] : node;
                float4 a = als4[s];
                l4.x = lrelu(a.x + aldn.x); l4.y = lrelu(a.y + aldn.y);
                l4.z = lrelu(a.z + aldn.z); l4.w = lrelu(a.w + aldn.w);
            }
#pragma unroll
            for (int off = 32; off > 0; off >>= 1) {
                l4.x = fmaxf(l4.x, __shfl_xor(l4.x, off));
                l4.y = fmaxf(l4.y, __shfl_xor(l4.y, off));
                l4.z = fmaxf(l4.z, __shfl_xor(l4.z, off));
                l4.w = fmaxf(l4.w, __shfl_xor(l4.w, off));
            }
            m4.x = fmaxf(m4.x, l4.x); m4.y = fmaxf(m4.y, l4.y);
            m4.z = fmaxf(m4.z, l4.z); m4.w = fmaxf(m4.w, l4.w);
        }
        d4 = make_float4(0.f, 0.f, 0.f, 0.f);
        for (int base = 0; base < tot; base += 64) {
            int j = base + lane;
            int s = node;
            float4 w4 = make_float4(0.f, 0.f, 0.f, 0.f);
            if (j < tot) {
                if (j < deg) s = csrsrc[r0 + j];
                float4 a = als4[s];
                w4.x = expf(lrelu(a.x + aldn.x) - m4.x);
                w4.y = expf(lrelu(a.y + aldn.y) - m4.y);
                w4.z = expf(lrelu(a.z + aldn.z) - m4.z);
                w4.w = expf(lrelu(a.w + aldn.w) - m4.w);
            }
            float4 p4 = w4;
#pragma unroll
            for (int off = 32; off > 0; off >>= 1) {
                p4.x += __shfl_xor(p4.x, off);
                p4.y += __shfl_xor(p4.y, off);
                p4.z += __shfl_xor(p4.z, off);
                p4.w += __shfl_xor(p4.w, off);
            }
            d4.x += p4.x; d4.y += p4.y; d4.z += p4.z; d4.w += p4.w;
            int lim = min(64, tot - base);
            for (int j2 = 0; j2 < lim; ++j2) {
                int sj = __shfl(s, j2);
                float w0 = __shfl(w4.x, j2), w1 = __shfl(w4.y, j2);
                float w2 = __shfl(w4.z, j2), w3 = __shfl(w4.w, j2);
                float wj = (head < 2) ? (head == 0 ? w0 : w1) : (head == 2 ? w2 : w3);
                const uint4 pk = *((const uint4*)(h + (size_t)sj * 512) + lane);
                const __half2* p2 = (const __half2*)&pk;
                float2 f0 = __half22float2(p2[0]);
                float2 f1 = __half22float2(p2[1]);
                float2 f2 = __half22float2(p2[2]);
                float2 f3 = __half22float2(p2[3]);
                acc[0] += wj * f0.x; acc[1] += wj * f0.y;
                acc[2] += wj * f1.x; acc[3] += wj * f1.y;
                acc[4] += wj * f2.x; acc[5] += wj * f2.y;
                acc[6] += wj * f3.x; acc[7] += wj * f3.y;
            }
        }
    }

    const float dsel = (head < 2) ? (head == 0 ? d4.x : d4.y) : (head == 2 ? d4.z : d4.w);
    const float inv = 1.f / dsel;
    const float4 b0 = ((const float4*)bias)[lane * 2];
    const float4 b1 = ((const float4*)bias)[lane * 2 + 1];
    float v[8];
    v[0] = acc[0] * inv + b0.x; v[1] = acc[1] * inv + b0.y;
    v[2] = acc[2] * inv + b0.z; v[3] = acc[3] * inv + b0.w;
    v[4] = acc[4] * inv + b1.x; v[5] = acc[5] * inv + b1.y;
    v[6] = acc[6] * inv + b1.z; v[7] = acc[7] * inv + b1.w;
    uint4 ph, pl;
    us* hps = (us*)&ph;
    us* lps = (us*)&pl;
#pragma unroll
    for (int k = 0; k < 8; ++k) {
        float e = (v[k] > 0.f) ? v[k] : expm1f(v[k]);
        us hb = f2bf(e);
        hps[k] = hb;
        lps[k] = f2bf(e - bf2f(hb));
    }
    *(uint4*)(x1hi + (size_t)node * 512 + lane * 8) = ph;
    *(uint4*)(x1lo + (size_t)node * 512 + lane * 8) = pl;
}

// ---------- layer-2 fused agg + relu + graph-max-pool (fp16 features), one wave/node ----------
__global__ __launch_bounds__(256) void agg2_k(const __half* __restrict__ h,
                                              const float* __restrict__ als,
                                              const float* __restrict__ ald,
                                              const int* __restrict__ rowptr,
                                              const int* __restrict__ csrsrc,
                                              const float* __restrict__ bias,
                                              const int* __restrict__ batch,
                                              int* __restrict__ pooled) {
    __shared__ int   ss[4][64];
    __shared__ float ws[4][64];
    const int node = (blockIdx.x * blockDim.x + threadIdx.x) >> 6;
    if (node >= N_NODES) return;
    const int lane = threadIdx.x & 63;
    const int wv = threadIdx.x >> 6;
    const int r0 = rowptr[node];
    const int deg = rowptr[node + 1] - r0;
    const int tot = deg + 1;
    const float aldn = ald[node];

    float acc0 = 0.f, acc1 = 0.f;
    float denom;

    if (tot <= 64) {
        int s = node;
        if (lane < deg) s = csrsrc[r0 + lane];
        float l = -1e30f, w = 0.f;
        if (lane < tot) l = lrelu(als[s] + aldn);
        float m = l;
#pragma unroll
        for (int off = 32; off > 0; off >>= 1) m = fmaxf(m, __shfl_xor(m, off));
        if (lane < tot) w = expf(l - m);
        denom = w;
#pragma unroll
        for (int off = 32; off > 0; off >>= 1) denom += __shfl_xor(denom, off);
        ss[wv][lane] = s;
        ws[wv][lane] = w;
        for (int j = 0; j < tot; ++j) {
            int sj = ss[wv][j];
            float wj = ws[wv][j];
            float2 f = __half22float2(((const __half2*)(h + (size_t)sj * 128))[lane]);
            acc0 += wj * f.x;
            acc1 += wj * f.y;
        }
    } else {
        float m = -1e30f;
        for (int base = 0; base < tot; base += 64) {
            int j = base + lane;
            float l = -1e30f;
            if (j < tot) {
                int s = (j < deg) ? csrsrc[r0 + j] : node;
                l = lrelu(als[s] + aldn);
            }
#pragma unroll
            for (int off = 32; off > 0; off >>= 1) l = fmaxf(l, __shfl_xor(l, off));
            m = fmaxf(m, l);
        }
        denom = 0.f;
        for (int base = 0; base < tot; base += 64) {
            int j = base + lane;
            int s = node;
            float w = 0.f;
            if (j < tot) {
                if (j < deg) s = csrsrc[r0 + j];
                w = expf(lrelu(als[s] + aldn) - m);
            }
            float ws2 = w;
#pragma unroll
            for (int off = 32; off > 0; off >>= 1) ws2 += __shfl_xor(ws2, off);
            denom += ws2;
            int lim = min(64, tot - base);
            for (int j2 = 0; j2 < lim; ++j2) {
                int sj = __shfl(s, j2);
                float wj = __shfl(w, j2);
                float2 f = __half22float2(((const __half2*)(h + (size_t)sj * 128))[lane]);
                acc0 += wj * f.x;
                acc1 += wj * f.y;
            }
        }
    }

    const float inv = 1.f / denom;
    float v0 = fmaxf(acc0 * inv + bias[lane * 2], 0.f);
    float v1 = fmaxf(acc1 * inv + bias[lane * 2 + 1], 0.f);
    int* pb = pooled + batch[node] * 128;
    atomicMax(&pb[lane * 2], __float_as_int(v0));
    atomicMax(&pb[lane * 2 + 1], __float_as_int(v1));
}

// ---------- final MLP head: one block per graph ----------
__global__ __launch_bounds__(64) void fc_k(const float* __restrict__ pooled,
                                           const float* __restrict__ w1,
                                           const float* __restrict__ b1,
                                           const float* __restrict__ w2,
                                           const float* __restrict__ b2,
                                           float* __restrict__ out) {
    int g = blockIdx.x;
    __shared__ float p[128];
    int t = threadIdx.x;
    p[t] = pooled[g * 128 + t];
    p[t + 64] = pooled[g * 128 + 64 + t];
    __syncthreads();
    float acc = 0.f;
    if (t < 16) {
        float s = b1[t];
        for (int c = 0; c < 128; ++c) s += p[c] * w1[c * 16 + t];
        s = fmaxf(s, 0.f);
        acc = s * w2[t];
    }
#pragma unroll
    for (int off = 8; off > 0; off >>= 1) acc += __shfl_down(acc, off);
    if (t == 0) out[g] = acc + b2[0];
}

extern "C" void kernel_launch(void* const* d_in, const int* in_sizes, int n_in,
                              void* d_out, int out_size, void* d_ws, size_t ws_size,
                              hipStream_t stream) {
    const float* x      = (const float*)d_in[0];
    const int*   ei     = (const int*)d_in[1];
    const int*   batch  = (const int*)d_in[2];
    const float* W1     = (const float*)d_in[3];
    const float* a_src1 = (const float*)d_in[4];
    const float* a_dst1 = (const float*)d_in[5];
    const float* b1     = (const float*)d_in[6];
    const float* W2     = (const float*)d_in[7];
    const float* a_src2 = (const float*)d_in[8];
    const float* a_dst2 = (const float*)d_in[9];
    const float* b2     = (const float*)d_in[10];
    const float* fc1w   = (const float*)d_in[11];
    const float* fc1b   = (const float*)d_in[12];
    const float* fc2w   = (const float*)d_in[13];
    const float* fc2b   = (const float*)d_in[14];
    float* out = (float*)d_out;

    const int* src = ei;
    const int* dst = ei + E_EDGES;

    // ---- workspace layout (4-byte units) ----
    int*   cnt    = (int*)d_ws;                     // 20,000 (zero region start)
    int*   cur    = cnt + 20000;                    // 20,000
    int*   pooled = cur + 20000;                    // 32,768
    // zero region = 72,768 * 4 = 291,072 bytes
    int*   rowptr = pooled + 32768;                 // 20,004
    int*   csrsrc = rowptr + 20004;                 // 320,000
    __half* h1h   = (__half*)(csrsrc + 320000);     // 10,240,000 halfs
    __half* h2h   = h1h + 10240000;                 //  2,560,000 halfs
    float* als1   = (float*)(h2h + 2560000);        //     80,000
    float* ald1   = als1 + 80000;                   //     80,000
    float* als2   = ald1 + 80000;                   //     20,000
    float* ald2   = als2 + 20000;                   //     20,000
    us* xhi   = (us*)(ald2 + 20000);                //  2,560,000 us
    us* xlo   = xhi + 2560000;                      //  2,560,000
    us* w1thi = xlo + 2560000;                      //     65,536
    us* w1tlo = w1thi + 65536;                      //     65,536
    us* w2thi = w1tlo + 65536;                      //     65,536
    us* w2tlo = w2thi + 65536;                      //     65,536
    us* x1hi  = w2tlo + 65536;                      // 10,240,000
    us* x1lo  = x1hi + 10240000;                    // 10,240,000

    (void)hipMemsetAsync(d_ws, 0, 72768 * 4, stream);

    // ---- CSR build + canonical sort ----
    cnt_k<<<(E_EDGES + 255) / 256, 256, 0, stream>>>(dst, cnt);
    scan_k<<<1, 256, 0, stream>>>(cnt, rowptr);
    scat_k<<<(E_EDGES + 255) / 256, 256, 0, stream>>>(src, dst, rowptr, cur, csrsrc);
    sortb_k<<<N_NODES / 4, 256, 0, stream>>>(rowptr, csrsrc);

    // ---- splits (bf16 hi/lo) ----
    splitall_k<<<(N_NODES * 128 + 255) / 256, 256, 0, stream>>>(
        x, xhi, xlo, W1, w1thi, w1tlo, W2, w2thi, w2tlo);

    // ---- layer 1: h1 = x @ W1 (split-bf16 MFMA), fp16 out ----
    mgemm_k<__half><<<dim3(313, 4), 256, 0, stream>>>(xhi, xlo, w1thi, w1tlo,
                                                      N_NODES, 512, 128, h1h);

    al16_k<<<(N_NODES * H1HEADS) / 4, 256, 0, stream>>>(h1h, a_src1, a_dst1, als1, ald1,
                                                        N_NODES * H1HEADS, H1HEADS);

    agg1_k<<<N_NODES / 4, 256, 0, stream>>>(h1h, (const float4*)als1, (const float4*)ald1,
                                            rowptr, csrsrc, b1, x1hi, x1lo);

    // ---- layer 2: h2 = x1 @ W2 (split-bf16 MFMA), fp16 out ----
    mgemm_k<__half><<<dim3(313, 1), 256, 0, stream>>>(x1hi, x1lo, w2thi, w2tlo,
                                                      N_NODES, 128, 512, h2h);

    al16_k<<<N_NODES / 4, 256, 0, stream>>>(h2h, a_src2, a_dst2, als2, ald2, N_NODES, 1);

    agg2_k<<<N_NODES / 4, 256, 0, stream>>>(h2h, als2, ald2, rowptr, csrsrc, b2,
                                            batch, pooled);

    // ---- head ----
    fc_k<<<G_GRAPHS, 64, 0, stream>>>((const float*)pooled, fc1w, fc1b, fc2w, fc2b, out);
}

// Round 8
// 325.240 us; speedup vs baseline: 1.1289x; 1.1289x over previous
//
#include <hip/hip_runtime.h>
#include <hip/hip_fp16.h>

#define N_NODES 20000
#define E_EDGES 320000
#define D_DIM   128
#define H1HEADS 4
#define G_GRAPHS 256
#define SLOPE   0.2f

typedef _Float16 h8 __attribute__((ext_vector_type(8)));
typedef float float4v __attribute__((ext_vector_type(4)));

// ---------------- CSR build ----------------
__global__ void cnt_k(const int* __restrict__ dst, int* __restrict__ cnt) {
    int e = blockIdx.x * blockDim.x + threadIdx.x;
    if (e < E_EDGES) atomicAdd(&cnt[dst[e]], 1);
}

__global__ __launch_bounds__(256) void scan_k(const int* __restrict__ cnt,
                                              int* __restrict__ rowptr) {
    __shared__ int s[256];
    const int t = threadIdx.x;
    const int CH = (N_NODES + 255) / 256;   // 79
    int base = t * CH;
    int sum = 0;
    for (int i = 0; i < CH; ++i) {
        int idx = base + i;
        if (idx < N_NODES) sum += cnt[idx];
    }
    s[t] = sum;
    __syncthreads();
    for (int off = 1; off < 256; off <<= 1) {
        int v = (t >= off) ? s[t - off] : 0;
        __syncthreads();
        s[t] += v;
        __syncthreads();
    }
    int run = (t > 0) ? s[t - 1] : 0;
    for (int i = 0; i < CH; ++i) {
        int idx = base + i;
        if (idx < N_NODES) { rowptr[idx] = run; run += cnt[idx]; }
    }
    if (t == 255) rowptr[N_NODES] = run;
}

__global__ void scat_k(const int* __restrict__ src, const int* __restrict__ dst,
                       const int* __restrict__ rowptr, int* __restrict__ cur,
                       int* __restrict__ csrsrc) {
    int e = blockIdx.x * blockDim.x + threadIdx.x;
    if (e >= E_EDGES) return;
    int d = dst[e];
    int p = rowptr[d] + atomicAdd(&cur[d], 1);
    csrsrc[p] = src[e];
}

// ---------- 64-lane bitonic sort (ascending) ----------
__device__ __forceinline__ int bitonic64(int key, int lane) {
#pragma unroll
    for (int k = 2; k <= 64; k <<= 1) {
#pragma unroll
        for (int j = k >> 1; j > 0; j >>= 1) {
            int other = __shfl_xor(key, j);
            bool up = ((lane & k) == 0);
            bool lower = ((lane & j) == 0);
            int mn = min(key, other), mx = max(key, other);
            key = (up == lower) ? mn : mx;
        }
    }
    return key;
}

// ---------- canonical per-bucket sort of csrsrc (deg < 64 empirically guaranteed) ----------
__global__ __launch_bounds__(256) void sortb_k(const int* __restrict__ rowptr,
                                               int* __restrict__ csrsrc) {
    const int node = (blockIdx.x * blockDim.x + threadIdx.x) >> 6;
    if (node >= N_NODES) return;
    const int lane = threadIdx.x & 63;
    const int r0 = rowptr[node];
    const int deg = rowptr[node + 1] - r0;
    if (deg <= 1 || deg > 64) return;
    int key = 0x7FFFFFFF;
    if (lane < deg) key = csrsrc[r0 + lane];
    key = bitonic64(key, lane);
    if (lane < deg) csrsrc[r0 + lane] = key;
}

// ---------- fused split: x -> fp16 hi/lo; W1,W2 -> transposed fp16 ----------
__global__ void splitall_k(const float* __restrict__ x, __half* __restrict__ xhi,
                           __half* __restrict__ xlo,
                           const float* __restrict__ W1, __half* __restrict__ w1t,
                           const float* __restrict__ W2, __half* __restrict__ w2t) {
    int i = blockIdx.x * blockDim.x + threadIdx.x;
    if (i < N_NODES * 128) {
        float v = x[i];
        __half h = __float2half(v);
        xhi[i] = h;
        xlo[i] = __float2half(v - __half2float(h));
    }
    if (i < 128 * 512) {
        {   // W1 [128 x 512] -> T [512 x 128]
            int k = i >> 9, n = i & 511;
            w1t[n * 128 + k] = __float2half(W1[i]);
        }
        {   // W2 [512 x 128] -> T [128 x 512]
            int k = i >> 7, n = i & 127;
            w2t[n * 512 + k] = __float2half(W2[i]);
        }
    }
}

// ---------- MFMA GEMM: C[M,N] = (Ahi+Alo)[M,K] * B[K,N] ----------
// A: fp16 hi/lo (exact fp32 to 2^-22), LDS-staged. B: fp16 TRANSPOSED [N x K],
// read directly from global (L2-resident weights). 2-pass f16 MFMA, fp32 acc.
// Tile 64(M) x 128(N), K-chunks of 64. 4 waves: (wm,wn) -> 2 m-tiles x 4 n-tiles.
__device__ __forceinline__ void store_val(__half* p, float v) { *p = __float2half(v); }
__device__ __forceinline__ void store_val(float* p, float v) { *p = v; }

template <typename OT>
__global__ __launch_bounds__(256) void fgemm_k(const __half* __restrict__ Ahi,
                                               const __half* __restrict__ Alo,
                                               const __half* __restrict__ BT,
                                               const int M, const int N, const int K,
                                               OT* __restrict__ C) {
    constexpr int SA = 72;   // LDS row stride in halfs (64 + 8 pad, 16B-aligned rows)
    __shared__ __half Ah[64 * SA], Al[64 * SA];   // 18.4 KB total
    const int t = threadIdx.x;
    const int wave = t >> 6, lane = t & 63;
    const int q = lane >> 4, rr = lane & 15;
    const int row0 = blockIdx.x * 64;
    const int col0 = blockIdx.y * 128;
    const int wm = wave & 1, wn = wave >> 1;

    float4v acc[2][4];
#pragma unroll
    for (int i = 0; i < 2; ++i)
#pragma unroll
        for (int j = 0; j < 4; ++j) acc[i][j] = (float4v){0.f, 0.f, 0.f, 0.f};

    for (int kc = 0; kc < K; kc += 64) {
        __syncthreads();
        // stage A tile (64 rows x 64 k) hi+lo: 512 8-half macros each
#pragma unroll
        for (int i = 0; i < 2; ++i) {
            int u = t + i * 256;
            int m = u >> 3, mac = u & 7;
            int r = row0 + m;
            uint4 vh = make_uint4(0, 0, 0, 0), vl = make_uint4(0, 0, 0, 0);
            if (r < M) {
                vh = *(const uint4*)(Ahi + (size_t)r * K + kc + mac * 8);
                vl = *(const uint4*)(Alo + (size_t)r * K + kc + mac * 8);
            }
            *(uint4*)(Ah + m * SA + mac * 8) = vh;
            *(uint4*)(Al + m * SA + mac * 8) = vl;
        }
        __syncthreads();
#pragma unroll
        for (int ks = 0; ks < 2; ++ks) {
            const int ko = ks * 32 + q * 8;
            h8 ah[2], alo[2], bh[4];
#pragma unroll
            for (int mt = 0; mt < 2; ++mt) {
                int m = (wm * 2 + mt) * 16 + rr;
                ah[mt]  = *(const h8*)(Ah + m * SA + ko);
                alo[mt] = *(const h8*)(Al + m * SA + ko);
            }
#pragma unroll
            for (int nt = 0; nt < 4; ++nt) {
                int n = (wn * 4 + nt) * 16 + rr;
                bh[nt] = *(const h8*)(BT + (size_t)(col0 + n) * K + kc + ko);
            }
#pragma unroll
            for (int mt = 0; mt < 2; ++mt)
#pragma unroll
                for (int nt = 0; nt < 4; ++nt) {
                    acc[mt][nt] = __builtin_amdgcn_mfma_f32_16x16x32_f16(
                        ah[mt], bh[nt], acc[mt][nt], 0, 0, 0);
                    acc[mt][nt] = __builtin_amdgcn_mfma_f32_16x16x32_f16(
                        alo[mt], bh[nt], acc[mt][nt], 0, 0, 0);
                }
        }
    }
    // epilogue: C/D layout col=lane&15, row=q*4+reg
#pragma unroll
    for (int mt = 0; mt < 2; ++mt) {
#pragma unroll
        for (int reg = 0; reg < 4; ++reg) {
            int r = row0 + (wm * 2 + mt) * 16 + q * 4 + reg;
            if (r < M) {
#pragma unroll
                for (int nt = 0; nt < 4; ++nt) {
                    int c = col0 + (wn * 4 + nt) * 16 + rr;
                    store_val(&C[(size_t)r * N + c], acc[mt][nt][reg]);
                }
            }
        }
    }
}

// ---------- attention dots, fp16 features: one wave per row of 128 ----------
__global__ __launch_bounds__(256) void al16_k(const __half* __restrict__ h,
                                              const float* __restrict__ a_src,
                                              const float* __restrict__ a_dst,
                                              float* __restrict__ als,
                                              float* __restrict__ ald,
                                              const int NH, const int H) {
    int wid = (blockIdx.x * blockDim.x + threadIdx.x) >> 6;
    int lane = threadIdx.x & 63;
    if (wid >= NH) return;
    int hh = wid % H;
    const __half2* row = (const __half2*)(h + (size_t)wid * 128);
    float2 v = __half22float2(row[lane]);
    float2 as2 = ((const float2*)(a_src + hh * 128))[lane];
    float2 ad2 = ((const float2*)(a_dst + hh * 128))[lane];
    float s = v.x * as2.x + v.y * as2.y;
    float d = v.x * ad2.x + v.y * ad2.y;
#pragma unroll
    for (int off = 32; off > 0; off >>= 1) {
        s += __shfl_down(s, off);
        d += __shfl_down(d, off);
    }
    if (lane == 0) { als[wid] = s; ald[wid] = d; }
}

__device__ __forceinline__ float lrelu(float v) { return (v > 0.f) ? v : SLOPE * v; }

// ---------- layer-1 fused softmax + gather-aggregate: ONE WAVE PER NODE (4 heads) ----------
__global__ __launch_bounds__(256) void agg1_k(const __half* __restrict__ h,
                                              const float4* __restrict__ als4,
                                              const float4* __restrict__ ald4,
                                              const int* __restrict__ rowptr,
                                              const int* __restrict__ csrsrc,
                                              const float* __restrict__ bias,
                                              __half* __restrict__ x1hi,
                                              __half* __restrict__ x1lo) {
    __shared__ int   ss[4][64];
    __shared__ float ws[4][64][4];
    const int node = (blockIdx.x * blockDim.x + threadIdx.x) >> 6;
    if (node >= N_NODES) return;
    const int lane = threadIdx.x & 63;
    const int wv = threadIdx.x >> 6;
    const int head = lane >> 4;
    const int r0 = rowptr[node];
    const int deg = rowptr[node + 1] - r0;
    const int tot = deg + 1;
    const float4 aldn = ald4[node];

    float acc[8] = {};
    float4 d4;

    if (tot <= 64) {
        int s = node;
        if (lane < deg) s = csrsrc[r0 + lane];
        float4 l4 = make_float4(-1e30f, -1e30f, -1e30f, -1e30f);
        if (lane < tot) {
            float4 a = als4[s];
            l4.x = lrelu(a.x + aldn.x); l4.y = lrelu(a.y + aldn.y);
            l4.z = lrelu(a.z + aldn.z); l4.w = lrelu(a.w + aldn.w);
        }
        float4 m4 = l4;
#pragma unroll
        for (int off = 32; off > 0; off >>= 1) {
            m4.x = fmaxf(m4.x, __shfl_xor(m4.x, off));
            m4.y = fmaxf(m4.y, __shfl_xor(m4.y, off));
            m4.z = fmaxf(m4.z, __shfl_xor(m4.z, off));
            m4.w = fmaxf(m4.w, __shfl_xor(m4.w, off));
        }
        float4 w4 = make_float4(0.f, 0.f, 0.f, 0.f);
        if (lane < tot) {
            w4.x = expf(l4.x - m4.x); w4.y = expf(l4.y - m4.y);
            w4.z = expf(l4.z - m4.z); w4.w = expf(l4.w - m4.w);
        }
        d4 = w4;
#pragma unroll
        for (int off = 32; off > 0; off >>= 1) {
            d4.x += __shfl_xor(d4.x, off);
            d4.y += __shfl_xor(d4.y, off);
            d4.z += __shfl_xor(d4.z, off);
            d4.w += __shfl_xor(d4.w, off);
        }
        ss[wv][lane] = s;
        *(float4*)&ws[wv][lane][0] = w4;
        for (int j = 0; j < tot; ++j) {
            int sj = ss[wv][j];
            float wj = ws[wv][j][head];
            const uint4 pk = *((const uint4*)(h + (size_t)sj * 512) + lane);
            const __half2* p2 = (const __half2*)&pk;
            float2 f0 = __half22float2(p2[0]);
            float2 f1 = __half22float2(p2[1]);
            float2 f2 = __half22float2(p2[2]);
            float2 f3 = __half22float2(p2[3]);
            acc[0] += wj * f0.x; acc[1] += wj * f0.y;
            acc[2] += wj * f1.x; acc[3] += wj * f1.y;
            acc[4] += wj * f2.x; acc[5] += wj * f2.y;
            acc[6] += wj * f3.x; acc[7] += wj * f3.y;
        }
    } else {
        // unreachable in practice (max degree < 64); deterministic since csrsrc sorted
        float4 m4 = make_float4(-1e30f, -1e30f, -1e30f, -1e30f);
        for (int base = 0; base < tot; base += 64) {
            int j = base + lane;
            float4 l4 = make_float4(-1e30f, -1e30f, -1e30f, -1e30f);
            if (j < tot) {
                int s = (j < deg) ? csrsrc[r0 + j] : node;
                float4 a = als4[s];
                l4.x = lrelu(a.x + aldn.x); l4.y = lrelu(a.y + aldn.y);
                l4.z = lrelu(a.z + aldn.z); l4.w = lrelu(a.w + aldn.w);
            }
#pragma unroll
            for (int off = 32; off > 0; off >>= 1) {
                l4.x = fmaxf(l4.x, __shfl_xor(l4.x, off));
                l4.y = fmaxf(l4.y, __shfl_xor(l4.y, off));
                l4.z = fmaxf(l4.z, __shfl_xor(l4.z, off));
                l4.w = fmaxf(l4.w, __shfl_xor(l4.w, off));
            }
            m4.x = fmaxf(m4.x, l4.x); m4.y = fmaxf(m4.y, l4.y);
            m4.z = fmaxf(m4.z, l4.z); m4.w = fmaxf(m4.w, l4.w);
        }
        d4 = make_float4(0.f, 0.f, 0.f, 0.f);
        for (int base = 0; base < tot; base += 64) {
            int j = base + lane;
            int s = node;
            float4 w4 = make_float4(0.f, 0.f, 0.f, 0.f);
            if (j < tot) {
                if (j < deg) s = csrsrc[r0 + j];
                float4 a = als4[s];
                w4.x = expf(lrelu(a.x + aldn.x) - m4.x);
                w4.y = expf(lrelu(a.y + aldn.y) - m4.y);
                w4.z = expf(lrelu(a.z + aldn.z) - m4.z);
                w4.w = expf(lrelu(a.w + aldn.w) - m4.w);
            }
            float4 p4 = w4;
#pragma unroll
            for (int off = 32; off > 0; off >>= 1) {
                p4.x += __shfl_xor(p4.x, off);
                p4.y += __shfl_xor(p4.y, off);
                p4.z += __shfl_xor(p4.z, off);
                p4.w += __shfl_xor(p4.w, off);
            }
            d4.x += p4.x; d4.y += p4.y; d4.z += p4.z; d4.w += p4.w;
            int lim = min(64, tot - base);
            for (int j2 = 0; j2 < lim; ++j2) {
                int sj = __shfl(s, j2);
                float w0 = __shfl(w4.x, j2), w1 = __shfl(w4.y, j2);
                float w2 = __shfl(w4.z, j2), w3 = __shfl(w4.w, j2);
                float wj = (head < 2) ? (head == 0 ? w0 : w1) : (head == 2 ? w2 : w3);
                const uint4 pk = *((const uint4*)(h + (size_t)sj * 512) + lane);
                const __half2* p2 = (const __half2*)&pk;
                float2 f0 = __half22float2(p2[0]);
                float2 f1 = __half22float2(p2[1]);
                float2 f2 = __half22float2(p2[2]);
                float2 f3 = __half22float2(p2[3]);
                acc[0] += wj * f0.x; acc[1] += wj * f0.y;
                acc[2] += wj * f1.x; acc[3] += wj * f1.y;
                acc[4] += wj * f2.x; acc[5] += wj * f2.y;
                acc[6] += wj * f3.x; acc[7] += wj * f3.y;
            }
        }
    }

    const float dsel = (head < 2) ? (head == 0 ? d4.x : d4.y) : (head == 2 ? d4.z : d4.w);
    const float inv = 1.f / dsel;
    const float4 b0 = ((const float4*)bias)[lane * 2];
    const float4 b1 = ((const float4*)bias)[lane * 2 + 1];
    float v[8];
    v[0] = acc[0] * inv + b0.x; v[1] = acc[1] * inv + b0.y;
    v[2] = acc[2] * inv + b0.z; v[3] = acc[3] * inv + b0.w;
    v[4] = acc[4] * inv + b1.x; v[5] = acc[5] * inv + b1.y;
    v[6] = acc[6] * inv + b1.z; v[7] = acc[7] * inv + b1.w;
    uint4 ph, pl;
    __half* hps = (__half*)&ph;
    __half* lps = (__half*)&pl;
#pragma unroll
    for (int k = 0; k < 8; ++k) {
        float e = (v[k] > 0.f) ? v[k] : expm1f(v[k]);
        __half hb = __float2half(e);
        hps[k] = hb;
        lps[k] = __float2half(e - __half2float(hb));
    }
    *(uint4*)(x1hi + (size_t)node * 512 + lane * 8) = ph;
    *(uint4*)(x1lo + (size_t)node * 512 + lane * 8) = pl;
}

// ---------- layer-2 fused agg + relu + graph-max-pool (fp16 features) ----------
__global__ __launch_bounds__(256) void agg2_k(const __half* __restrict__ h,
                                              const float* __restrict__ als,
                                              const float* __restrict__ ald,
                                              const int* __restrict__ rowptr,
                                              const int* __restrict__ csrsrc,
                                              const float* __restrict__ bias,
                                              const int* __restrict__ batch,
                                              int* __restrict__ pooled) {
    __shared__ int   ss[4][64];
    __shared__ float ws[4][64];
    const int node = (blockIdx.x * blockDim.x + threadIdx.x) >> 6;
    if (node >= N_NODES) return;
    const int lane = threadIdx.x & 63;
    const int wv = threadIdx.x >> 6;
    const int r0 = rowptr[node];
    const int deg = rowptr[node + 1] - r0;
    const int tot = deg + 1;
    const float aldn = ald[node];

    float acc0 = 0.f, acc1 = 0.f;
    float denom;

    if (tot <= 64) {
        int s = node;
        if (lane < deg) s = csrsrc[r0 + lane];
        float l = -1e30f, w = 0.f;
        if (lane < tot) l = lrelu(als[s] + aldn);
        float m = l;
#pragma unroll
        for (int off = 32; off > 0; off >>= 1) m = fmaxf(m, __shfl_xor(m, off));
        if (lane < tot) w = expf(l - m);
        denom = w;
#pragma unroll
        for (int off = 32; off > 0; off >>= 1) denom += __shfl_xor(denom, off);
        ss[wv][lane] = s;
        ws[wv][lane] = w;
        for (int j = 0; j < tot; ++j) {
            int sj = ss[wv][j];
            float wj = ws[wv][j];
            float2 f = __half22float2(((const __half2*)(h + (size_t)sj * 128))[lane]);
            acc0 += wj * f.x;
            acc1 += wj * f.y;
        }
    } else {
        float m = -1e30f;
        for (int base = 0; base < tot; base += 64) {
            int j = base + lane;
            float l = -1e30f;
            if (j < tot) {
                int s = (j < deg) ? csrsrc[r0 + j] : node;
                l = lrelu(als[s] + aldn);
            }
#pragma unroll
            for (int off = 32; off > 0; off >>= 1) l = fmaxf(l, __shfl_xor(l, off));
            m = fmaxf(m, l);
        }
        denom = 0.f;
        for (int base = 0; base < tot; base += 64) {
            int j = base + lane;
            int s = node;
            float w = 0.f;
            if (j < tot) {
                if (j < deg) s = csrsrc[r0 + j];
                w = expf(lrelu(als[s] + aldn) - m);
            }
            float ws2 = w;
#pragma unroll
            for (int off = 32; off > 0; off >>= 1) ws2 += __shfl_xor(ws2, off);
            denom += ws2;
            int lim = min(64, tot - base);
            for (int j2 = 0; j2 < lim; ++j2) {
                int sj = __shfl(s, j2);
                float wj = __shfl(w, j2);
                float2 f = __half22float2(((const __half2*)(h + (size_t)sj * 128))[lane]);
                acc0 += wj * f.x;
                acc1 += wj * f.y;
            }
        }
    }

    const float inv = 1.f / denom;
    float v0 = fmaxf(acc0 * inv + bias[lane * 2], 0.f);
    float v1 = fmaxf(acc1 * inv + bias[lane * 2 + 1], 0.f);
    int* pb = pooled + batch[node] * 128;
    atomicMax(&pb[lane * 2], __float_as_int(v0));
    atomicMax(&pb[lane * 2 + 1], __float_as_int(v1));
}

// ---------- final MLP head: one block per graph ----------
__global__ __launch_bounds__(64) void fc_k(const float* __restrict__ pooled,
                                           const float* __restrict__ w1,
                                           const float* __restrict__ b1,
                                           const float* __restrict__ w2,
                                           const float* __restrict__ b2,
                                           float* __restrict__ out) {
    int g = blockIdx.x;
    __shared__ float p[128];
    int t = threadIdx.x;
    p[t] = pooled[g * 128 + t];
    p[t + 64] = pooled[g * 128 + 64 + t];
    __syncthreads();
    float acc = 0.f;
    if (t < 16) {
        float s = b1[t];
        for (int c = 0; c < 128; ++c) s += p[c] * w1[c * 16 + t];
        s = fmaxf(s, 0.f);
        acc = s * w2[t];
    }
#pragma unroll
    for (int off = 8; off > 0; off >>= 1) acc += __shfl_down(acc, off);
    if (t == 0) out[g] = acc + b2[0];
}

extern "C" void kernel_launch(void* const* d_in, const int* in_sizes, int n_in,
                              void* d_out, int out_size, void* d_ws, size_t ws_size,
                              hipStream_t stream) {
    const float* x      = (const float*)d_in[0];
    const int*   ei     = (const int*)d_in[1];
    const int*   batch  = (const int*)d_in[2];
    const float* W1     = (const float*)d_in[3];
    const float* a_src1 = (const float*)d_in[4];
    const float* a_dst1 = (const float*)d_in[5];
    const float* b1     = (const float*)d_in[6];
    const float* W2     = (const float*)d_in[7];
    const float* a_src2 = (const float*)d_in[8];
    const float* a_dst2 = (const float*)d_in[9];
    const float* b2     = (const float*)d_in[10];
    const float* fc1w   = (const float*)d_in[11];
    const float* fc1b   = (const float*)d_in[12];
    const float* fc2w   = (const float*)d_in[13];
    const float* fc2b   = (const float*)d_in[14];
    float* out = (float*)d_out;

    const int* src = ei;
    const int* dst = ei + E_EDGES;

    // ---- workspace layout (4-byte units) ----
    int*   cnt    = (int*)d_ws;                     // 20,000 (zero region start)
    int*   cur    = cnt + 20000;                    // 20,000
    int*   pooled = cur + 20000;                    // 32,768
    // zero region = 72,768 * 4 = 291,072 bytes
    int*   rowptr = pooled + 32768;                 // 20,004
    int*   csrsrc = rowptr + 20004;                 // 320,000
    __half* h1h   = (__half*)(csrsrc + 320000);     // 10,240,000 halfs
    __half* h2h   = h1h + 10240000;                 //  2,560,000 halfs
    float* als1   = (float*)(h2h + 2560000);        //     80,000
    float* ald1   = als1 + 80000;                   //     80,000
    float* als2   = ald1 + 80000;                   //     20,000
    float* ald2   = als2 + 20000;                   //     20,000
    __half* xhi   = (__half*)(ald2 + 20000);        //  2,560,000 halfs
    __half* xlo   = xhi + 2560000;                  //  2,560,000
    __half* w1t   = xlo + 2560000;                  //     65,536
    __half* w2t   = w1t + 65536;                    //     65,536
    __half* x1hi  = w2t + 65536;                    // 10,240,000
    __half* x1lo  = x1hi + 10240000;                // 10,240,000

    (void)hipMemsetAsync(d_ws, 0, 72768 * 4, stream);

    // ---- CSR build + canonical sort ----
    cnt_k<<<(E_EDGES + 255) / 256, 256, 0, stream>>>(dst, cnt);
    scan_k<<<1, 256, 0, stream>>>(cnt, rowptr);
    scat_k<<<(E_EDGES + 255) / 256, 256, 0, stream>>>(src, dst, rowptr, cur, csrsrc);
    sortb_k<<<N_NODES / 4, 256, 0, stream>>>(rowptr, csrsrc);

    // ---- splits (fp16) ----
    splitall_k<<<(N_NODES * 128 + 255) / 256, 256, 0, stream>>>(
        x, xhi, xlo, W1, w1t, W2, w2t);

    // ---- layer 1: h1 = x @ W1 (fp16 2-pass MFMA), fp16 out ----
    fgemm_k<__half><<<dim3(313, 4), 256, 0, stream>>>(xhi, xlo, w1t,
                                                      N_NODES, 512, 128, h1h);

    al16_k<<<(N_NODES * H1HEADS) / 4, 256, 0, stream>>>(h1h, a_src1, a_dst1, als1, ald1,
                                                        N_NODES * H1HEADS, H1HEADS);

    agg1_k<<<N_NODES / 4, 256, 0, stream>>>(h1h, (const float4*)als1, (const float4*)ald1,
                                            rowptr, csrsrc, b1, x1hi, x1lo);

    // ---- layer 2: h2 = x1 @ W2 (fp16 2-pass MFMA), fp16 out ----
    fgemm_k<__half><<<dim3(313, 1), 256, 0, stream>>>(x1hi, x1lo, w2t,
                                                      N_NODES, 128, 512, h2h);

    al16_k<<<N_NODES / 4, 256, 0, stream>>>(h2h, a_src2, a_dst2, als2, ald2, N_NODES, 1);

    agg2_k<<<N_NODES / 4, 256, 0, stream>>>(h2h, als2, ald2, rowptr, csrsrc, b2,
                                            batch, pooled);

    // ---- head ----
    fc_k<<<G_GRAPHS, 64, 0, stream>>>((const float*)pooled, fc1w, fc1b, fc2w, fc2b, out);
}